// Round 1
// baseline (376.223 us; speedup 1.0000x reference)
//
#include <hip/hip_runtime.h>
#include <hip/hip_fp16.h>
#include <math.h>

#define NQ 14
#define NL 6
#define NT 512
#define BATCH 1024
#define NGATES (NL * NQ)
#define NK 16     // half2 regs per re/im = 32 amps/thread
#define NCOEF 20  // precomputed half2 coeffs (as f32-bit u32) per gate

// amp p = (tid<<5) | j, j=0..31. j bits 0-3 = reg k, j bit 4 = packing bit.
// storage bit map: 0-3 local k; 4 packing; 5-10 lane (tid bit p-5); 11-13 wave.
// Wire w <-> amp bit P = 13-w.
//
// R20 (this round): eliminate the 3 wave-bit rots per layer. All rots in a
// layer commute; ring F_l and bit-swaps are GF(2)-linear. Per layer:
//   phase A: rot wires 13..3 (storage bits 0..10, register/shuffle only)
//   perm S:  swap storage bits 11,12,13 <-> 0,1,2 (one LDS scatter)
//   phase B: rot wires 2,1,0 now at local bits 0,1,2
//   perm F_l∘S: ring + swap-back in ONE LDS scatter (layers 0..4)
// Last ring folded into measurement sign = bit13(F5(S(s))), a GF(2) mask.
// LDS round trips per layer: 4 -> 2, barriers 8 -> 4; float4 staging gone.

using H2 = __half2;

__device__ __forceinline__ unsigned h2u(H2 v){ return __builtin_bit_cast(unsigned, v); }
__device__ __forceinline__ H2 u2h(unsigned x){ return __builtin_bit_cast(H2, x); }
__device__ __forceinline__ float h2f(H2 v){ return __builtin_bit_cast(float, v); }
__device__ __forceinline__ H2 f2h(float x){ return __builtin_bit_cast(H2, x); }
__device__ __forceinline__ H2 shflx(H2 v, int m){
    return u2h((unsigned)__shfl_xor((int)h2u(v), m, 64));
}

// image of index v under layer-l CNOT ring (gate order w=0..13) — GF(2)-linear
__device__ constexpr int ring_F(int l, int v) {
    int r = (l % 13) + 1;
    for (int w = 0; w < NQ; ++w) {
        int pc = 13 - w, pt = 13 - ((w + r) % NQ);
        v ^= ((v >> pc) & 1) << pt;
    }
    return v;
}
// swap storage bits 11,12,13 <-> 0,1,2 (involution)
__device__ constexpr int swapS(int v) {
    return (v & 0x07F8) | ((v & 7) << 11) | ((v >> 11) & 7);
}
// perm applied after phase B: mode<0 -> S (mid-layer), else F_mode∘S (inter-layer)
__device__ constexpr int pmapf(int mode, int v) {
    int u = swapS(v);
    return (mode < 0) ? u : ring_F(mode, u);
}
// measurement sign mask: bit13(F5(S(s))) = parity(s & M13)
__device__ constexpr int calc_m13() {
    int m = 0;
    for (int v = 0; v < NQ; ++v)
        if ((ring_F(NL - 1, swapS(1 << v)) >> 13) & 1) m |= 1 << v;
    return m;
}

// ---- prep: per-gate half2 coefficient table (batch-shared) into d_ws ----
// [0..7]=bc(m0..m7)  [8..11]=bc(-m1,-m3,-m5,-m7)
// [12]=(m0,m6) [13]=(m1,m7) [14]=(m2,m4) [15]=(m3,m5) [16]=(-m1,-m7) [17]=(-m3,-m5)
__global__ void prep_kernel(const float* __restrict__ wts, float* __restrict__ gm) {
    int g = blockIdx.x * blockDim.x + threadIdx.x;
    if (g < NGATES) {
        float phi = wts[g*3+0], th = wts[g*3+1], om = wts[g*3+2];
        float c = cosf(0.5f*th), s = sinf(0.5f*th);
        float a = 0.5f*(phi+om), bb = 0.5f*(phi-om);
        float ca = cosf(a), sa = sinf(a);
        float cb = cosf(bb), sb = sinf(bb);
        float m0 = c*ca, m1 = -c*sa;   // m00
        float m2 = -s*cb, m3 = -s*sb;  // m01
        float m4 = s*cb,  m5 = -s*sb;  // m10
        float m6 = c*ca,  m7 = c*sa;   // m11
        float* o = gm + g*NCOEF;
        o[0] = h2f(__float2half2_rn(m0)); o[1] = h2f(__float2half2_rn(m1));
        o[2] = h2f(__float2half2_rn(m2)); o[3] = h2f(__float2half2_rn(m3));
        o[4] = h2f(__float2half2_rn(m4)); o[5] = h2f(__float2half2_rn(m5));
        o[6] = h2f(__float2half2_rn(m6)); o[7] = h2f(__float2half2_rn(m7));
        o[8]  = h2f(__float2half2_rn(-m1));
        o[9]  = h2f(__float2half2_rn(-m3));
        o[10] = h2f(__float2half2_rn(-m5));
        o[11] = h2f(__float2half2_rn(-m7));
        o[12] = h2f(__floats2half2_rn(m0, m6));
        o[13] = h2f(__floats2half2_rn(m1, m7));
        o[14] = h2f(__floats2half2_rn(m2, m4));
        o[15] = h2f(__floats2half2_rn(m3, m5));
        o[16] = h2f(__floats2half2_rn(-m1, -m7));
        o[17] = h2f(__floats2half2_rn(-m3, -m5));
        o[18] = 0.f; o[19] = 0.f;
    }
}

// ---- Rot on storage bit P (P <= 10: never touches LDS) ----
template<int P>
__device__ __forceinline__ void rot_gate(H2 (&pr)[NK], H2 (&pi)[NK],
                                         const float* __restrict__ cw, int tid) {
    if constexpr (P < 4) {
        constexpr int M = 1 << P;
        H2 h0=f2h(cw[0]), h1=f2h(cw[1]), h2v=f2h(cw[2]), h3=f2h(cw[3]);
        H2 h4=f2h(cw[4]), h5=f2h(cw[5]), h6=f2h(cw[6]), h7=f2h(cw[7]);
        H2 nh1=f2h(cw[8]), nh3=f2h(cw[9]), nh5=f2h(cw[10]), nh7=f2h(cw[11]);
        #pragma unroll
        for (int i = 0; i < NK/2; ++i) {
            int k0 = ((i >> P) << (P+1)) | (i & (M-1));
            int k1 = k0 | M;
            H2 r0=pr[k0], i0=pi[k0], r1=pr[k1], i1=pi[k1];
            pr[k0] = __hfma2(h0,r0,__hfma2(nh1,i0,__hfma2(h2v,r1,__hmul2(nh3,i1))));
            pi[k0] = __hfma2(h0,i0,__hfma2(h1,r0,__hfma2(h2v,i1,__hmul2(h3,r1))));
            pr[k1] = __hfma2(h4,r0,__hfma2(nh5,i0,__hfma2(h6,r1,__hmul2(nh7,i1))));
            pi[k1] = __hfma2(h4,i0,__hfma2(h5,r0,__hfma2(h6,i1,__hmul2(h7,r1))));
        }
    } else if constexpr (P == 4) {
        // packing-bit rot: half-swap + per-half coeff H2s (all preloaded)
        H2 cAr=f2h(cw[12]), cAi=f2h(cw[13]), cBr=f2h(cw[14]), cBi=f2h(cw[15]);
        H2 nAi=f2h(cw[16]), nBi=f2h(cw[17]);
        #pragma unroll
        for (int k = 0; k < NK; ++k) {
            unsigned Ar = h2u(pr[k]), Ai = h2u(pi[k]);
            H2 sr = u2h((Ar>>16)|(Ar<<16)), si = u2h((Ai>>16)|(Ai<<16));
            H2 r = pr[k], i = pi[k];
            pr[k] = __hfma2(cAr,r,__hfma2(nAi,i,__hfma2(cBr,sr,__hmul2(nBi,si))));
            pi[k] = __hfma2(cAr,i,__hfma2(cAi,r,__hfma2(cBr,si,__hmul2(cBi,sr))));
        }
    } else {
        constexpr int LM = 1 << (P-5);
        int bit = (tid >> (P-5)) & 1;
        H2 a   = f2h(bit ? cw[6]  : cw[0]);
        H2 ai2 = f2h(bit ? cw[7]  : cw[1]);
        H2 nai = f2h(bit ? cw[11] : cw[8]);
        H2 b2  = f2h(bit ? cw[4]  : cw[2]);
        H2 bi2 = f2h(bit ? cw[5]  : cw[3]);
        H2 nbi = f2h(bit ? cw[10] : cw[9]);
        #pragma unroll
        for (int k = 0; k < NK; ++k) {
            H2 r = pr[k], i = pi[k];
            H2 qr = shflx(r, LM), qi = shflx(i, LM);
            pr[k] = __hfma2(a,r,__hfma2(nai,i,__hfma2(b2,qr,__hmul2(nbi,qi))));
            pi[k] = __hfma2(a,i,__hfma2(ai2,r,__hfma2(b2,qi,__hmul2(bi2,qr))));
        }
    }
}

// ---- one GF(2)-linear LDS permutation (scatter write, swizzled read) ----
// swizzle a(w) = w ^ ((w>>5)&31): reads conflict-free; S-writes conflict-free
// by construction (low addr bits become waveconst ^ t[0:4]).
template<int MODE>
__device__ __forceinline__ void perm_exchange(H2 (&pr)[NK], H2 (&pi)[NK],
                                              int tid, unsigned* ub) {
    int base = pmapf(MODE, tid << 5);   // linear: M(p) = M(tid<<5) ^ M(j)
    #pragma unroll
    for (int k = 0; k < NK; ++k) {
        unsigned wlo = (h2u(pr[k]) & 0xFFFFu) | (h2u(pi[k]) << 16);      // amp j=k
        unsigned whi = (h2u(pr[k]) >> 16) | (h2u(pi[k]) & 0xFFFF0000u);  // amp j=k|16
        int flo = base ^ pmapf(MODE, k);        // folds: k is a literal after unroll
        int fhi = base ^ pmapf(MODE, k | 16);
        ub[flo ^ ((flo >> 5) & 31)] = wlo;
        ub[fhi ^ ((fhi >> 5) & 31)] = whi;
    }
    __syncthreads();
    int sw = tid & 31;
    #pragma unroll
    for (int k = 0; k < NK; ++k) {
        unsigned wlo = ub[((tid << 5) | k) ^ sw];
        unsigned whi = ub[((tid << 5) | (k | 16)) ^ sw];
        pr[k] = u2h((wlo & 0xFFFFu) | (whi << 16));
        pi[k] = u2h((wlo >> 16) | (whi & 0xFFFF0000u));
    }
    __syncthreads();
}

// ---- compile-time circuit drivers ----
template<int L, int P>
__device__ __forceinline__ void do_rotsA(H2 (&pr)[NK], H2 (&pi)[NK],
                                         const float* __restrict__ gm, int tid) {
    rot_gate<P>(pr, pi, gm + (L*NQ + (13-P))*NCOEF, tid);   // wire 13-P at bit P
    if constexpr (P < 10) do_rotsA<L, P+1>(pr, pi, gm, tid);
}

template<int L>
__device__ __forceinline__ void do_layer(H2 (&pr)[NK], H2 (&pi)[NK],
                                         const float* __restrict__ gm, int tid,
                                         unsigned* ub) {
    do_rotsA<L, 0>(pr, pi, gm, tid);          // wires 13..3
    perm_exchange<-1>(pr, pi, tid, ub);       // S: bits 11-13 <-> 0-2
    rot_gate<0>(pr, pi, gm + (L*NQ + 2)*NCOEF, tid);  // wire 2 now at bit 0
    rot_gate<1>(pr, pi, gm + (L*NQ + 1)*NCOEF, tid);  // wire 1 at bit 1
    rot_gate<2>(pr, pi, gm + (L*NQ + 0)*NCOEF, tid);  // wire 0 at bit 2
    if constexpr (L < NL-1) {
        perm_exchange<L>(pr, pi, tid, ub);    // F_L ∘ S: ring + back to canonical
        do_layer<L+1>(pr, pi, gm, tid, ub);
    }
    // last layer: ring folded into measurement sign
}

__global__ void __launch_bounds__(NT)
qsim_kernel(
    const float* __restrict__ x,
    const float* __restrict__ gm,
    float* __restrict__ out)
{
    __shared__ unsigned ub[NT * NK * 2];   // 64 KB -> 2 blocks/CU
    const int tid = threadIdx.x;
    const int b = blockIdx.x;
    const float* xb = x + b * NQ;

    // ---- direct product-state init (fp32 math, pack to fp16) ----
    H2 pr[NK], pi[NK];
    {
        float cr = 1.f, ci = 0.f;
        #pragma unroll
        for (int bb = 0; bb < 9; ++bb) {       // tid bit bb = amp bit 5+bb = wire 8-bb
            float s, c; __sincosf(0.5f * xb[8 - bb], &s, &c);
            if ((tid >> bb) & 1) { float nr = s*ci, ni = -s*cr; cr = nr; ci = ni; }
            else                 { cr *= c; ci *= c; }
        }
        float lc[4], ls[4];                     // k bit bb = wire 13-bb
        #pragma unroll
        for (int bb = 0; bb < 4; ++bb) __sincosf(0.5f * xb[13 - bb], &ls[bb], &lc[bb]);
        float s9, c9; __sincosf(0.5f * xb[9], &s9, &c9);   // packing bit = wire 9
        #pragma unroll
        for (int k = 0; k < NK; ++k) {
            float rr = cr, ii = ci;
            #pragma unroll
            for (int bb = 0; bb < 4; ++bb) {
                if ((k >> bb) & 1) { float nr = ls[bb]*ii, ni = -ls[bb]*rr; rr = nr; ii = ni; }
                else               { rr *= lc[bb]; ii *= lc[bb]; }
            }
            pr[k] = __floats2half2_rn(rr*c9,  s9*ii);
            pi[k] = __floats2half2_rn(ii*c9, -s9*rr);
        }
    }

    do_layer<0>(pr, pi, gm, tid, ub);

    // ---- <Z0>: state is in layout S; sign = bit13(F5(S(s))) = parity(s&M13) ----
    constexpr int M13 = calc_m13();
    int tpar = __builtin_popcount((tid << 5) & M13) & 1;
    float acc = 0.f;
    #pragma unroll
    for (int k = 0; k < NK; ++k) {
        float a=__low2float(pr[k]), c=__high2float(pr[k]);
        float d=__low2float(pi[k]), e=__high2float(pi[k]);
        float vlo = a*a + d*d, vhi = c*c + e*e;
        int slo = tpar ^ (__builtin_popcount(k & M13) & 1);          // folds per k
        int shi = tpar ^ (__builtin_popcount((k | 16) & M13) & 1);
        acc += slo ? -vlo : vlo;
        acc += shi ? -vhi : vhi;
    }
    #pragma unroll
    for (int off = 32; off > 0; off >>= 1) acc += __shfl_down(acc, off, 64);
    __syncthreads();
    float* f = (float*)ub;
    if ((tid & 63) == 0) f[tid >> 6] = acc;
    __syncthreads();
    if (tid == 0) {
        float s = 0.f;
        #pragma unroll
        for (int w = 0; w < NT/64; ++w) s += f[w];
        out[b] = s;
    }
}

extern "C" void kernel_launch(void* const* d_in, const int* in_sizes, int n_in,
                              void* d_out, int out_size, void* d_ws, size_t ws_size,
                              hipStream_t stream) {
    const float* x = (const float*)d_in[0];   // (1024, 14) float32
    const float* w = (const float*)d_in[1];   // (6, 14, 3) float32
    float* out = (float*)d_out;               // (1024,) float32
    float* gm = (float*)d_ws;                 // 84*20 floats of packed coeffs

    prep_kernel<<<1, 128, 0, stream>>>(w, gm);
    qsim_kernel<<<BATCH, NT, 0, stream>>>(x, gm, out);
}